// Round 5
// baseline (1006.484 us; speedup 1.0000x reference)
//
#include <hip/hip_runtime.h>
#include <hip/hip_bf16.h>

typedef __attribute__((ext_vector_type(8))) short bf16x8;
typedef __attribute__((ext_vector_type(4))) float f32x4;
typedef __attribute__((ext_vector_type(8))) unsigned short u16x8;

#define B_DIM 8192
#define H_DIM 1024
#define K_DIM 2048
#define N_DIM 4096
#define BH (B_DIM * H_DIM)

__device__ __forceinline__ unsigned short f2bf(float f) {
    union { float f; unsigned u; } v; v.f = f;
    unsigned r = v.u + 0x7FFFu + ((v.u >> 16) & 1u);   // round-to-nearest-even
    return (unsigned short)(r >> 16);
}

__device__ __forceinline__ void gload16(const void* g, void* l) {
    __builtin_amdgcn_global_load_lds(
        (const __attribute__((address_space(1))) void*)g,
        (__attribute__((address_space(3))) void*)l, 16, 0, 0);
}

// ---------------------------------------------------------------------------
// prep (unchanged from round 4 — banked −10 µs): blocks [0,2048) pack [x|h]
// fp32 -> bf16 A[8192][2048]; blocks [2048,4096) transpose W=[Wx;Wh] -> bf16
// Bperm (gate-permuted B^T) via 64x64 LDS tile. One dispatch, nt input loads.
//   Bperm row map: n = gate*1024 + j; jb=j>>5, jj=j&31 ->
//   R = jb*128 + (jj>>4)*64 + gate*16 + (jj&15),  Bperm[R][k] = W[k][n]
// ---------------------------------------------------------------------------
__global__ void prep(const float* __restrict__ x, const float* __restrict__ h,
                     const float* __restrict__ Wx, const float* __restrict__ Wh,
                     unsigned short* __restrict__ Abf, unsigned short* __restrict__ Bperm) {
    __shared__ float tile[64][65];
    const int t = threadIdx.x;
    if (blockIdx.x < 2048) {
        const int gid0 = blockIdx.x * 256 + t;
#pragma unroll
        for (int it = 0; it < 4; ++it) {
            int gid = gid0 + it * (2048 * 256);
            size_t e = (size_t)gid * 8;
            int m   = gid >> 8;                     // row (2048 elems/row)
            int col = (gid & 255) * 8;
            int p   = col >> 10;                    // 0 = x half, 1 = h half
            int k   = col & 1023;
            const f32x4* src = (const f32x4*)((p ? h : x) + (size_t)m * 1024 + k);
            f32x4 v0 = __builtin_nontemporal_load(src);
            f32x4 v1 = __builtin_nontemporal_load(src + 1);
            u16x8 o = { f2bf(v0.x), f2bf(v0.y), f2bf(v0.z), f2bf(v0.w),
                        f2bf(v1.x), f2bf(v1.y), f2bf(v1.z), f2bf(v1.w) };
            *(u16x8*)(Abf + e) = o;
        }
        return;
    }
    const int bz = blockIdx.x - 2048;
    const int k0 = (bz & 31) * 64;                  // 32 tiles over K
    const int n0 = (bz >> 5) * 64;                  // 64 tiles over N
#pragma unroll
    for (int it = 0; it < 4; ++it) {
        int lin = it * 256 + t;                     // 0..1023 float4 slots
        int kl  = lin >> 4;
        int n4  = lin & 15;
        int k   = k0 + kl;
        const f32x4* src = (const f32x4*)((k < 1024)
                              ? (Wx + (size_t)k * 4096 + n0 + n4 * 4)
                              : (Wh + (size_t)(k - 1024) * 4096 + n0 + n4 * 4));
        f32x4 v = __builtin_nontemporal_load(src);
        tile[kl][n4 * 4 + 0] = v.x;
        tile[kl][n4 * 4 + 1] = v.y;
        tile[kl][n4 * 4 + 2] = v.z;
        tile[kl][n4 * 4 + 3] = v.w;
    }
    __syncthreads();
#pragma unroll
    for (int it = 0; it < 2; ++it) {
        int lin = it * 256 + t;                     // 0..511
        int nl  = lin >> 3;
        int ch  = lin & 7;
        int n    = n0 + nl;
        int gate = n >> 10;
        int j    = n & 1023;
        int jb   = j >> 5;
        int jj   = j & 31;
        int R    = jb * 128 + (jj >> 4) * 64 + gate * 16 + (jj & 15);
        u16x8 o;
#pragma unroll
        for (int q = 0; q < 8; ++q) o[q] = f2bf(tile[ch * 8 + q][nl]);
        *(u16x8*)(Bperm + (size_t)R * 2048 + k0 + ch * 8) = o;
    }
}

// ---------------------------------------------------------------------------
// fused GEMM + LSTM epilogue — round-0 structure (anchor 149 µs) with three
// additive tweaks:
//  1. __launch_bounds__(256,5): 5 blocks/CU (5 x 32 KiB LDS = full 160 KiB
//     pool; VGPR cap 96 >= our use). Round-4 occupancy was 35% (~2.8
//     blocks/CU); more resident blocks absorb the per-K-step vmcnt drain.
//  2. Loop-invariant hoisting: 16 LDS fragment offsets precomputed; 8 staging
//     pointers advance by +64 elems/iter (VALUBusy was 34% on addr recompute).
//  3. cin nt-loads in epilogue (read-once; don't evict Abf/Bperm from L3).
// 128x128 tile, BK=64, 4 waves, 16x16x32 bf16, XOR-swizzled LDS (0 conflicts).
// ---------------------------------------------------------------------------
__global__ __launch_bounds__(256, 5) void lstm_fused(
    const unsigned short* __restrict__ Abf,   // [8192][2048] bf16
    const unsigned short* __restrict__ Bperm, // [4096][2048] bf16 (permuted B^T)
    const float* __restrict__ bx, const float* __restrict__ bh,
    const float* __restrict__ cin, float* __restrict__ out) {
    __shared__ unsigned short lsA[128 * 64];
    __shared__ unsigned short lsB[128 * 64];

    const int tid  = threadIdx.x;
    const int wave = tid >> 6;
    const int lane = tid & 63;
    const int m0 = blockIdx.x * 128;
    const int jb = blockIdx.y;                  // 0..31
    const int wm = wave >> 1;
    const int wn = wave & 1;

    f32x4 acc[4][4];
#pragma unroll
    for (int i = 0; i < 4; ++i)
#pragma unroll
        for (int j = 0; j < 4; ++j) acc[i][j] = (f32x4){0.f, 0.f, 0.f, 0.f};

    const int sRow   = tid >> 3;                              // 0..31 (+ it*32)
    const int sChunk = (((tid & 7) ^ ((tid >> 3) & 7))) * 8;  // swizzled source col

    // Hoisted staging pointers: advance by 64 elems (128 B) per K-step.
    const unsigned short* aSrc[4];
    const unsigned short* bSrc[4];
    unsigned short* aDst[4];
    unsigned short* bDst[4];
#pragma unroll
    for (int it = 0; it < 4; ++it) {
        aSrc[it] = Abf   + (size_t)(m0 + it * 32 + sRow) * K_DIM + sChunk;
        bSrc[it] = Bperm + (size_t)(jb * 128 + it * 32 + sRow) * K_DIM + sChunk;
        aDst[it] = lsA + it * 2048 + wave * 512;
        bDst[it] = lsB + it * 2048 + wave * 512;
    }

    const int fRow  = lane & 15;
    const int qBase = lane >> 4;                // 0..3
    const int rx    = fRow & 7;                 // row XOR key

    // Hoisted loop-invariant LDS fragment offsets (elements).
    int aOff[2][4], bOff[2][4];
#pragma unroll
    for (int ks = 0; ks < 2; ++ks) {
        const int qPhys = (ks * 4 + qBase) ^ rx;
#pragma unroll
        for (int tq = 0; tq < 4; ++tq) {
            aOff[ks][tq] = (wm * 64 + tq * 16 + fRow) * 64 + qPhys * 8;
            bOff[ks][tq] = (wn * 64 + tq * 16 + fRow) * 64 + qPhys * 8;
        }
    }

    for (int kt = 0; kt < 32; ++kt) {
#pragma unroll
        for (int it = 0; it < 4; ++it) {
            gload16(aSrc[it], aDst[it]);
            gload16(bSrc[it], bDst[it]);
            aSrc[it] += 64;
            bSrc[it] += 64;
        }
        __syncthreads();
#pragma unroll
        for (int ks = 0; ks < 2; ++ks) {
            bf16x8 af[4], bfr[4];
#pragma unroll
            for (int tm = 0; tm < 4; ++tm)
                af[tm] = *(const bf16x8*)(lsA + aOff[ks][tm]);
#pragma unroll
            for (int tn = 0; tn < 4; ++tn)
                bfr[tn] = *(const bf16x8*)(lsB + bOff[ks][tn]);
#pragma unroll
            for (int tm = 0; tm < 4; ++tm)
#pragma unroll
                for (int tn = 0; tn < 4; ++tn)
                    acc[tm][tn] = __builtin_amdgcn_mfma_f32_16x16x32_bf16(
                        af[tm], bfr[tn], acc[tm][tn], 0, 0, 0);
        }
        __syncthreads();
    }

    // Epilogue: tn indexes gate {i,f,g,o}; j fixed per lane.
    const int j = jb * 32 + wn * 16 + fRow;
    const float b_i = bx[j] + bh[j];
    const float b_f = bx[1024 + j] + bh[1024 + j];
    const float b_g = bx[2048 + j] + bh[2048 + j];
    const float b_o = bx[3072 + j] + bh[3072 + j];
#pragma unroll
    for (int tm = 0; tm < 4; ++tm) {
#pragma unroll
        for (int r = 0; r < 4; ++r) {
            const int row = m0 + wm * 64 + tm * 16 + (lane >> 4) * 4 + r;
            float vi = acc[tm][0][r] + b_i;
            float vf = acc[tm][1][r] + b_f;
            float vg = acc[tm][2][r] + b_g;
            float vo = acc[tm][3][r] + b_o;
            float ig = 1.f / (1.f + __expf(-vi));
            float fg = 1.f / (1.f + __expf(-vf));
            float e2g = __expf(2.f * fminf(fmaxf(vg, -15.f), 15.f));
            float gg = (e2g - 1.f) / (e2g + 1.f);
            float og = 1.f / (1.f + __expf(-vo));
            float cv = __builtin_nontemporal_load(cin + (size_t)row * 1024 + j);
            float cn = fg * cv + ig * gg;
            float e2c = __expf(2.f * fminf(fmaxf(cn, -15.f), 15.f));
            float hn = og * ((e2c - 1.f) / (e2c + 1.f));
            out[(size_t)row * 1024 + j] = og;
            out[(size_t)BH + (size_t)row * 1024 + j] = hn;
            out[(size_t)2 * BH + (size_t)row * 1024 + j] = cn;
        }
    }
}

extern "C" void kernel_launch(void* const* d_in, const int* in_sizes, int n_in,
                              void* d_out, int out_size, void* d_ws, size_t ws_size,
                              hipStream_t stream) {
    const float* x  = (const float*)d_in[0];
    const float* h  = (const float*)d_in[1];
    const float* c  = (const float*)d_in[2];
    const float* Wx = (const float*)d_in[3];
    const float* Wh = (const float*)d_in[4];
    const float* bx = (const float*)d_in[5];
    const float* bh = (const float*)d_in[6];
    float* out = (float*)d_out;

    unsigned short* Abf   = (unsigned short*)d_ws;                                      // 32 MB
    unsigned short* Bperm = (unsigned short*)((char*)d_ws + (size_t)B_DIM * K_DIM * 2); // 16 MB

    hipLaunchKernelGGL(prep, dim3(4096), dim3(256), 0, stream, x, h, Wx, Wh, Abf, Bperm);
    hipLaunchKernelGGL(lstm_fused, dim3(B_DIM / 128, 32), dim3(256), 0, stream,
                       Abf, Bperm, bx, bh, c, out);
}

// Round 6
// 339.574 us; speedup vs baseline: 2.9640x; 2.9640x over previous
//
#include <hip/hip_runtime.h>
#include <hip/hip_bf16.h>

typedef __attribute__((ext_vector_type(8))) short bf16x8;
typedef __attribute__((ext_vector_type(4))) float f32x4;
typedef __attribute__((ext_vector_type(8))) unsigned short u16x8;

#define B_DIM 8192
#define H_DIM 1024
#define K_DIM 2048
#define N_DIM 4096
#define BH (B_DIM * H_DIM)

__device__ __forceinline__ unsigned short f2bf(float f) {
    union { float f; unsigned u; } v; v.f = f;
    unsigned r = v.u + 0x7FFFu + ((v.u >> 16) & 1u);   // round-to-nearest-even
    return (unsigned short)(r >> 16);
}

__device__ __forceinline__ void gload16(const void* g, void* l) {
    __builtin_amdgcn_global_load_lds(
        (const __attribute__((address_space(1))) void*)g,
        (__attribute__((address_space(3))) void*)l, 16, 0, 0);
}

// ---------------------------------------------------------------------------
// prep (round-4 known-good, banked −10 µs): blocks [0,2048) pack [x|h] fp32 ->
// bf16 A[8192][2048]; blocks [2048,4096) transpose W=[Wx;Wh] -> bf16 Bperm
// (gate-permuted B^T) via 64x64 LDS tile. One dispatch, nt input loads.
//   Bperm row map: n = gate*1024 + j; jb=j>>5, jj=j&31 ->
//   R = jb*128 + (jj>>4)*64 + gate*16 + (jj&15),  Bperm[R][k] = W[k][n]
// ---------------------------------------------------------------------------
__global__ void prep(const float* __restrict__ x, const float* __restrict__ h,
                     const float* __restrict__ Wx, const float* __restrict__ Wh,
                     unsigned short* __restrict__ Abf, unsigned short* __restrict__ Bperm) {
    __shared__ float tile[64][65];
    const int t = threadIdx.x;
    if (blockIdx.x < 2048) {
        const int gid0 = blockIdx.x * 256 + t;
#pragma unroll
        for (int it = 0; it < 4; ++it) {
            int gid = gid0 + it * (2048 * 256);
            size_t e = (size_t)gid * 8;
            int m   = gid >> 8;                     // row (2048 elems/row)
            int col = (gid & 255) * 8;
            int p   = col >> 10;                    // 0 = x half, 1 = h half
            int k   = col & 1023;
            const f32x4* src = (const f32x4*)((p ? h : x) + (size_t)m * 1024 + k);
            f32x4 v0 = __builtin_nontemporal_load(src);
            f32x4 v1 = __builtin_nontemporal_load(src + 1);
            u16x8 o = { f2bf(v0.x), f2bf(v0.y), f2bf(v0.z), f2bf(v0.w),
                        f2bf(v1.x), f2bf(v1.y), f2bf(v1.z), f2bf(v1.w) };
            *(u16x8*)(Abf + e) = o;
        }
        return;
    }
    const int bz = blockIdx.x - 2048;
    const int k0 = (bz & 31) * 64;                  // 32 tiles over K
    const int n0 = (bz >> 5) * 64;                  // 64 tiles over N
#pragma unroll
    for (int it = 0; it < 4; ++it) {
        int lin = it * 256 + t;                     // 0..1023 float4 slots
        int kl  = lin >> 4;
        int n4  = lin & 15;
        int k   = k0 + kl;
        const f32x4* src = (const f32x4*)((k < 1024)
                              ? (Wx + (size_t)k * 4096 + n0 + n4 * 4)
                              : (Wh + (size_t)(k - 1024) * 4096 + n0 + n4 * 4));
        f32x4 v = __builtin_nontemporal_load(src);
        tile[kl][n4 * 4 + 0] = v.x;
        tile[kl][n4 * 4 + 1] = v.y;
        tile[kl][n4 * 4 + 2] = v.z;
        tile[kl][n4 * 4 + 3] = v.w;
    }
    __syncthreads();
#pragma unroll
    for (int it = 0; it < 2; ++it) {
        int lin = it * 256 + t;                     // 0..511
        int nl  = lin >> 3;
        int ch  = lin & 7;
        int n    = n0 + nl;
        int gate = n >> 10;
        int j    = n & 1023;
        int jb   = j >> 5;
        int jj   = j & 31;
        int R    = jb * 128 + (jj >> 4) * 64 + gate * 16 + (jj & 15);
        u16x8 o;
#pragma unroll
        for (int q = 0; q < 8; ++q) o[q] = f2bf(tile[ch * 8 + q][nl]);
        *(u16x8*)(Bperm + (size_t)R * 2048 + k0 + ch * 8) = o;
    }
}

// ---------------------------------------------------------------------------
// fused GEMM + LSTM epilogue — round-0/round-4 anchor structure, VERBATIM
// loop body (148.6 µs measured, VGPR 64, MfmaUtil ~42%, 0 bank conflicts,
// ~3 blocks/CU). Round-5 falsified the occupancy lever: __launch_bounds__
// (256,5) forced VGPR cap 96 -> K-loop spill (VGPR 48, FETCH 1.37 GB,
// 832 µs). DO NOT raise the min-waves hint or hoist address arrays here.
// Only addition vs round-0: scalar nt-load of cin in the epilogue (read-once
// 32 MB stream; keeps Abf/Bperm L3-resident).
// 128x128 tile, BK=64, 4 waves, 16x16x32 bf16.
// XOR-swizzled LDS: physical chunk p holds logical (row=p>>3, c=(p&7)^(row&7))
// -> staging source column = ((tid&7) ^ ((tid>>3)&7)) * 8 (dest fixed lane*16),
//    fragment read offset = row*64 + 8*((ks*4 + (lane>>4)) ^ (row&7)).
// ---------------------------------------------------------------------------
__global__ __launch_bounds__(256, 4) void lstm_fused(
    const unsigned short* __restrict__ Abf,   // [8192][2048] bf16
    const unsigned short* __restrict__ Bperm, // [4096][2048] bf16 (permuted B^T)
    const float* __restrict__ bx, const float* __restrict__ bh,
    const float* __restrict__ cin, float* __restrict__ out) {
    __shared__ unsigned short lsA[128 * 64];
    __shared__ unsigned short lsB[128 * 64];

    const int tid  = threadIdx.x;
    const int wave = tid >> 6;
    const int lane = tid & 63;
    const int m0 = blockIdx.x * 128;
    const int jb = blockIdx.y;                  // 0..31
    const int wm = wave >> 1;
    const int wn = wave & 1;

    f32x4 acc[4][4];
#pragma unroll
    for (int i = 0; i < 4; ++i)
#pragma unroll
        for (int j = 0; j < 4; ++j) acc[i][j] = (f32x4){0.f, 0.f, 0.f, 0.f};

    const int sRow   = tid >> 3;                              // 0..31 (+ it*32)
    const int sChunk = (((tid & 7) ^ ((tid >> 3) & 7))) * 8;  // swizzled source col
    const int aBase = (m0 + sRow) * K_DIM + sChunk;
    const int bBase = (jb * 128 + sRow) * K_DIM + sChunk;

    const int fRow  = lane & 15;
    const int qBase = lane >> 4;                // 0..3
    const int rx    = fRow & 7;                 // row XOR key

    for (int kt = 0; kt < 32; ++kt) {
        const int kOff = kt * 64;
#pragma unroll
        for (int it = 0; it < 4; ++it) {
            gload16(Abf + aBase + it * (32 * K_DIM) + kOff, lsA + it * 2048 + wave * 512);
            gload16(Bperm + bBase + it * (32 * K_DIM) + kOff, lsB + it * 2048 + wave * 512);
        }
        __syncthreads();
#pragma unroll
        for (int ks = 0; ks < 2; ++ks) {
            bf16x8 af[4], bfr[4];
            const int qPhys = (ks * 4 + qBase) ^ rx;          // physical chunk
#pragma unroll
            for (int tm = 0; tm < 4; ++tm)
                af[tm] = *(const bf16x8*)(lsA + (wm * 64 + tm * 16 + fRow) * 64 + qPhys * 8);
#pragma unroll
            for (int tn = 0; tn < 4; ++tn)
                bfr[tn] = *(const bf16x8*)(lsB + (wn * 64 + tn * 16 + fRow) * 64 + qPhys * 8);
#pragma unroll
            for (int tm = 0; tm < 4; ++tm)
#pragma unroll
                for (int tn = 0; tn < 4; ++tn)
                    acc[tm][tn] = __builtin_amdgcn_mfma_f32_16x16x32_bf16(
                        af[tm], bfr[tn], acc[tm][tn], 0, 0, 0);
        }
        __syncthreads();
    }

    // Epilogue: tn indexes gate {i,f,g,o}; j fixed per lane.
    const int j = jb * 32 + wn * 16 + fRow;
    const float b_i = bx[j] + bh[j];
    const float b_f = bx[1024 + j] + bh[1024 + j];
    const float b_g = bx[2048 + j] + bh[2048 + j];
    const float b_o = bx[3072 + j] + bh[3072 + j];
#pragma unroll
    for (int tm = 0; tm < 4; ++tm) {
#pragma unroll
        for (int r = 0; r < 4; ++r) {
            const int row = m0 + wm * 64 + tm * 16 + (lane >> 4) * 4 + r;
            float vi = acc[tm][0][r] + b_i;
            float vf = acc[tm][1][r] + b_f;
            float vg = acc[tm][2][r] + b_g;
            float vo = acc[tm][3][r] + b_o;
            float ig = 1.f / (1.f + __expf(-vi));
            float fg = 1.f / (1.f + __expf(-vf));
            float e2g = __expf(2.f * fminf(fmaxf(vg, -15.f), 15.f));
            float gg = (e2g - 1.f) / (e2g + 1.f);
            float og = 1.f / (1.f + __expf(-vo));
            float cv = __builtin_nontemporal_load(cin + (size_t)row * 1024 + j);
            float cn = fg * cv + ig * gg;
            float e2c = __expf(2.f * fminf(fmaxf(cn, -15.f), 15.f));
            float hn = og * ((e2c - 1.f) / (e2c + 1.f));
            out[(size_t)row * 1024 + j] = og;
            out[(size_t)BH + (size_t)row * 1024 + j] = hn;
            out[(size_t)2 * BH + (size_t)row * 1024 + j] = cn;
        }
    }
}

extern "C" void kernel_launch(void* const* d_in, const int* in_sizes, int n_in,
                              void* d_out, int out_size, void* d_ws, size_t ws_size,
                              hipStream_t stream) {
    const float* x  = (const float*)d_in[0];
    const float* h  = (const float*)d_in[1];
    const float* c  = (const float*)d_in[2];
    const float* Wx = (const float*)d_in[3];
    const float* Wh = (const float*)d_in[4];
    const float* bx = (const float*)d_in[5];
    const float* bh = (const float*)d_in[6];
    float* out = (float*)d_out;

    unsigned short* Abf   = (unsigned short*)d_ws;                                      // 32 MB
    unsigned short* Bperm = (unsigned short*)((char*)d_ws + (size_t)B_DIM * K_DIM * 2); // 16 MB

    hipLaunchKernelGGL(prep, dim3(4096), dim3(256), 0, stream, x, h, Wx, Wh, Abf, Bperm);
    hipLaunchKernelGGL(lstm_fused, dim3(B_DIM / 128, 32), dim3(256), 0, stream,
                       Abf, Bperm, bx, bh, c, out);
}

// Round 7
// 329.050 us; speedup vs baseline: 3.0588x; 1.0320x over previous
//
#include <hip/hip_runtime.h>
#include <hip/hip_bf16.h>

typedef __attribute__((ext_vector_type(8))) short bf16x8;
typedef __attribute__((ext_vector_type(4))) float f32x4;
typedef __attribute__((ext_vector_type(8))) unsigned short u16x8;

#define B_DIM 8192
#define H_DIM 1024
#define K_DIM 2048
#define N_DIM 4096
#define BH (B_DIM * H_DIM)

__device__ __forceinline__ unsigned short f2bf(float f) {
    union { float f; unsigned u; } v; v.f = f;
    unsigned r = v.u + 0x7FFFu + ((v.u >> 16) & 1u);   // round-to-nearest-even
    return (unsigned short)(r >> 16);
}

__device__ __forceinline__ void gload16(const void* g, void* l) {
    __builtin_amdgcn_global_load_lds(
        (const __attribute__((address_space(1))) void*)g,
        (__attribute__((address_space(3))) void*)l, 16, 0, 0);
}

// ---------------------------------------------------------------------------
// prep (round-4 known-good): blocks [0,2048) pack [x|h] fp32 -> bf16
// A[8192][2048]; blocks [2048,4096) transpose W=[Wx;Wh] -> bf16 Bperm
// (gate-permuted B^T) via 64x64 LDS tile. One dispatch, nt input loads.
//   Bperm row map: n = gate*1024 + j; jb=j>>5, jj=j&31 ->
//   R = jb*128 + (jj>>4)*64 + gate*16 + (jj&15),  Bperm[R][k] = W[k][n]
// ---------------------------------------------------------------------------
__global__ void prep(const float* __restrict__ x, const float* __restrict__ h,
                     const float* __restrict__ Wx, const float* __restrict__ Wh,
                     unsigned short* __restrict__ Abf, unsigned short* __restrict__ Bperm) {
    __shared__ float tile[64][65];
    const int t = threadIdx.x;
    if (blockIdx.x < 2048) {
        const int gid0 = blockIdx.x * 256 + t;
#pragma unroll
        for (int it = 0; it < 4; ++it) {
            int gid = gid0 + it * (2048 * 256);
            size_t e = (size_t)gid * 8;
            int m   = gid >> 8;                     // row (2048 elems/row)
            int col = (gid & 255) * 8;
            int p   = col >> 10;                    // 0 = x half, 1 = h half
            int k   = col & 1023;
            const f32x4* src = (const f32x4*)((p ? h : x) + (size_t)m * 1024 + k);
            f32x4 v0 = __builtin_nontemporal_load(src);
            f32x4 v1 = __builtin_nontemporal_load(src + 1);
            u16x8 o = { f2bf(v0.x), f2bf(v0.y), f2bf(v0.z), f2bf(v0.w),
                        f2bf(v1.x), f2bf(v1.y), f2bf(v1.z), f2bf(v1.w) };
            *(u16x8*)(Abf + e) = o;
        }
        return;
    }
    const int bz = blockIdx.x - 2048;
    const int k0 = (bz & 31) * 64;                  // 32 tiles over K
    const int n0 = (bz >> 5) * 64;                  // 64 tiles over N
#pragma unroll
    for (int it = 0; it < 4; ++it) {
        int lin = it * 256 + t;                     // 0..1023 float4 slots
        int kl  = lin >> 4;
        int n4  = lin & 15;
        int k   = k0 + kl;
        const f32x4* src = (const f32x4*)((k < 1024)
                              ? (Wx + (size_t)k * 4096 + n0 + n4 * 4)
                              : (Wh + (size_t)(k - 1024) * 4096 + n0 + n4 * 4));
        f32x4 v = __builtin_nontemporal_load(src);
        tile[kl][n4 * 4 + 0] = v.x;
        tile[kl][n4 * 4 + 1] = v.y;
        tile[kl][n4 * 4 + 2] = v.z;
        tile[kl][n4 * 4 + 3] = v.w;
    }
    __syncthreads();
#pragma unroll
    for (int it = 0; it < 2; ++it) {
        int lin = it * 256 + t;                     // 0..511
        int nl  = lin >> 3;
        int ch  = lin & 7;
        int n    = n0 + nl;
        int gate = n >> 10;
        int j    = n & 1023;
        int jb   = j >> 5;
        int jj   = j & 31;
        int R    = jb * 128 + (jj >> 4) * 64 + gate * 16 + (jj & 15);
        u16x8 o;
#pragma unroll
        for (int q = 0; q < 8; ++q) o[q] = f2bf(tile[ch * 8 + q][nl]);
        *(u16x8*)(Bperm + (size_t)R * 2048 + k0 + ch * 8) = o;
    }
}

// ---------------------------------------------------------------------------
// fused GEMM + LSTM epilogue — round-0/round-4 anchor, VERBATIM (148.6 µs,
// VGPR 64, MfmaUtil ~42%, 0 bank conflicts, ~3 blocks/CU; 925 TF = the m97
// 128²/2-barrier structural ceiling). Falsified levers — do not retry:
//  * 256² 8-phase counted-vmcnt schedule: 183/192 µs (R1/R2) — 1 block/CU
//    kills the implicit 4-block overlap; fence fix made it worse.
//  * __launch_bounds__(256,5) + addr hoisting: VGPR cap 96 -> K-loop spill
//    (VGPR 48, FETCH 1.37 GB, 832 µs, R5).
//  * cin nt-load in epilogue: perturbs codegen (VGPR 64->56, +4 µs, R6).
//  * out nt-stores: WRITE 99->124 MB (R1), worse.
// 128x128 tile, BK=64, 4 waves, 16x16x32 bf16.
// XOR-swizzled LDS: physical chunk p holds logical (row=p>>3, c=(p&7)^(row&7))
// -> staging source column = ((tid&7) ^ ((tid>>3)&7)) * 8 (dest fixed lane*16),
//    fragment read offset = row*64 + 8*((ks*4 + (lane>>4)) ^ (row&7)).
// ---------------------------------------------------------------------------
__global__ __launch_bounds__(256, 4) void lstm_fused(
    const unsigned short* __restrict__ Abf,   // [8192][2048] bf16
    const unsigned short* __restrict__ Bperm, // [4096][2048] bf16 (permuted B^T)
    const float* __restrict__ bx, const float* __restrict__ bh,
    const float* __restrict__ cin, float* __restrict__ out) {
    __shared__ unsigned short lsA[128 * 64];
    __shared__ unsigned short lsB[128 * 64];

    const int tid  = threadIdx.x;
    const int wave = tid >> 6;
    const int lane = tid & 63;
    const int m0 = blockIdx.x * 128;
    const int jb = blockIdx.y;                  // 0..31
    const int wm = wave >> 1;
    const int wn = wave & 1;

    f32x4 acc[4][4];
#pragma unroll
    for (int i = 0; i < 4; ++i)
#pragma unroll
        for (int j = 0; j < 4; ++j) acc[i][j] = (f32x4){0.f, 0.f, 0.f, 0.f};

    const int sRow   = tid >> 3;                              // 0..31 (+ it*32)
    const int sChunk = (((tid & 7) ^ ((tid >> 3) & 7))) * 8;  // swizzled source col
    const int aBase = (m0 + sRow) * K_DIM + sChunk;
    const int bBase = (jb * 128 + sRow) * K_DIM + sChunk;

    const int fRow  = lane & 15;
    const int qBase = lane >> 4;                // 0..3
    const int rx    = fRow & 7;                 // row XOR key

    for (int kt = 0; kt < 32; ++kt) {
        const int kOff = kt * 64;
#pragma unroll
        for (int it = 0; it < 4; ++it) {
            gload16(Abf + aBase + it * (32 * K_DIM) + kOff, lsA + it * 2048 + wave * 512);
            gload16(Bperm + bBase + it * (32 * K_DIM) + kOff, lsB + it * 2048 + wave * 512);
        }
        __syncthreads();
#pragma unroll
        for (int ks = 0; ks < 2; ++ks) {
            bf16x8 af[4], bfr[4];
            const int qPhys = (ks * 4 + qBase) ^ rx;          // physical chunk
#pragma unroll
            for (int tm = 0; tm < 4; ++tm)
                af[tm] = *(const bf16x8*)(lsA + (wm * 64 + tm * 16 + fRow) * 64 + qPhys * 8);
#pragma unroll
            for (int tn = 0; tn < 4; ++tn)
                bfr[tn] = *(const bf16x8*)(lsB + (wn * 64 + tn * 16 + fRow) * 64 + qPhys * 8);
#pragma unroll
            for (int tm = 0; tm < 4; ++tm)
#pragma unroll
                for (int tn = 0; tn < 4; ++tn)
                    acc[tm][tn] = __builtin_amdgcn_mfma_f32_16x16x32_bf16(
                        af[tm], bfr[tn], acc[tm][tn], 0, 0, 0);
        }
        __syncthreads();
    }

    // Epilogue: tn indexes gate {i,f,g,o}; j fixed per lane.
    const int j = jb * 32 + wn * 16 + fRow;
    const float b_i = bx[j] + bh[j];
    const float b_f = bx[1024 + j] + bh[1024 + j];
    const float b_g = bx[2048 + j] + bh[2048 + j];
    const float b_o = bx[3072 + j] + bh[3072 + j];
#pragma unroll
    for (int tm = 0; tm < 4; ++tm) {
#pragma unroll
        for (int r = 0; r < 4; ++r) {
            const int row = m0 + wm * 64 + tm * 16 + (lane >> 4) * 4 + r;
            float vi = acc[tm][0][r] + b_i;
            float vf = acc[tm][1][r] + b_f;
            float vg = acc[tm][2][r] + b_g;
            float vo = acc[tm][3][r] + b_o;
            float ig = 1.f / (1.f + __expf(-vi));
            float fg = 1.f / (1.f + __expf(-vf));
            float e2g = __expf(2.f * fminf(fmaxf(vg, -15.f), 15.f));
            float gg = (e2g - 1.f) / (e2g + 1.f);
            float og = 1.f / (1.f + __expf(-vo));
            float cn = fg * cin[(size_t)row * 1024 + j] + ig * gg;
            float e2c = __expf(2.f * fminf(fmaxf(cn, -15.f), 15.f));
            float hn = og * ((e2c - 1.f) / (e2c + 1.f));
            out[(size_t)row * 1024 + j] = og;
            out[(size_t)BH + (size_t)row * 1024 + j] = hn;
            out[(size_t)2 * BH + (size_t)row * 1024 + j] = cn;
        }
    }
}

extern "C" void kernel_launch(void* const* d_in, const int* in_sizes, int n_in,
                              void* d_out, int out_size, void* d_ws, size_t ws_size,
                              hipStream_t stream) {
    const float* x  = (const float*)d_in[0];
    const float* h  = (const float*)d_in[1];
    const float* c  = (const float*)d_in[2];
    const float* Wx = (const float*)d_in[3];
    const float* Wh = (const float*)d_in[4];
    const float* bx = (const float*)d_in[5];
    const float* bh = (const float*)d_in[6];
    float* out = (float*)d_out;

    unsigned short* Abf   = (unsigned short*)d_ws;                                      // 32 MB
    unsigned short* Bperm = (unsigned short*)((char*)d_ws + (size_t)B_DIM * K_DIM * 2); // 16 MB

    hipLaunchKernelGGL(prep, dim3(4096), dim3(256), 0, stream, x, h, Wx, Wh, Abf, Bperm);
    hipLaunchKernelGGL(lstm_fused, dim3(B_DIM / 128, 32), dim3(256), 0, stream,
                       Abf, Bperm, bx, bh, c, out);
}